// Round 8
// baseline (591.102 us; speedup 1.0000x reference)
//
#include <hip/hip_runtime.h>
#include <hip/hip_bf16.h>
#include <hip/hip_fp16.h>
#include <type_traits>

#define N_NODES 100000
#define N_EDGES 1600000
#define LOG2E 1.44269504f

typedef _Float16 half8_t __attribute__((ext_vector_type(8)));
typedef _Float16 half4_t __attribute__((ext_vector_type(4)));
typedef float floatx4 __attribute__((ext_vector_type(4)));

// ---------------------------------------------------------------- fused count_deg + prep_w  (R2 schedule, best measured)
// blocks 0..6249: degree histogram.  blocks 6250..6601: weight transpose/pack.
// Wt1: 144 rows x 128. rows 0..127 = W1^T; 128..131 = W1·al1·log2e; 132..135 = W1·ar1·log2e; 136..143 = 0.
// Wt2: 208 rows x 128. rows 0..187 = W2^T; 188..191 = 0; 192..195 = W2·al2·log2e; 196..199 = W2·ar2·log2e.
__global__ void csr_prep(const int* __restrict__ dst, int* __restrict__ deg, int E,
                         const float* __restrict__ W1, const float* __restrict__ W2,
                         const float* __restrict__ al1, const float* __restrict__ ar1,
                         const float* __restrict__ al2, const float* __restrict__ ar2,
                         __half* __restrict__ Wt1, __half* __restrict__ Wt2) {
    const int b = blockIdx.x;
    if (b < 6250) {
        int i = b * 256 + threadIdx.x;
        if (i < E) atomicAdd(&deg[dst[i]], 1);
        return;
    }
    const int c = b - 6250;           // 0..351
    const int k = threadIdx.x;
    if (k >= 128) return;
    if (c < 128) {
        Wt1[c * 128 + k] = __float2half(W1[k * 128 + c]);
    } else if (c < 144) {
        int j = c - 128;
        float v = 0.f;
        if (j < 8) {
            int h = j & 3;
            const float* a = (j < 4) ? al1 : ar1;
            for (int d = 0; d < 32; ++d)
                v = fmaf(W1[k * 128 + h * 32 + d], a[h * 32 + d], v);
        }
        Wt1[c * 128 + k] = __float2half(v * LOG2E);
    } else if (c < 336) {
        int c2 = c - 144;  // 0..191
        float v = (c2 < 188) ? W2[k * 188 + c2] : 0.f;
        Wt2[c2 * 128 + k] = __float2half(v);
    } else {
        int j = c - 336;   // 0..15 -> Wt2 rows 192..207
        float v = 0.f;
        if (j < 8) {
            int h = j & 3;
            const float* a = (j < 4) ? al2 : ar2;
            for (int d = 0; d < 47; ++d)
                v = fmaf(W2[k * 188 + h * 47 + d], a[h * 47 + d], v);
        }
        Wt2[(192 + j) * 128 + k] = __float2half(v * LOG2E);
    }
}

__global__ void block_sums(const int* __restrict__ deg, int* __restrict__ bsum, int N) {
    __shared__ int ws[4];
    const int t = threadIdx.x;
    int i = blockIdx.x * 256 + t;
    int v = (i < N) ? deg[i] : 0;
    #pragma unroll
    for (int o = 32; o; o >>= 1) v += __shfl_down(v, o, 64);
    if ((t & 63) == 0) ws[t >> 6] = v;
    __syncthreads();
    if (t == 0) bsum[blockIdx.x] = ws[0] + ws[1] + ws[2] + ws[3];
}

__global__ void scan_bsum(int* __restrict__ bsum, int nb) {
    __shared__ int sh[512];
    const int t = threadIdx.x;
    sh[t] = (t < nb) ? bsum[t] : 0;
    __syncthreads();
    for (int o = 1; o < 512; o <<= 1) {
        int v = (t >= o) ? sh[t - o] : 0;
        __syncthreads();
        sh[t] += v;
        __syncthreads();
    }
    if (t < nb) bsum[t] = sh[t];
}

__global__ void scan_final(const int* __restrict__ deg, const int* __restrict__ bsum,
                           int* __restrict__ row_ptr, int* __restrict__ cursor, int N) {
    __shared__ int ws[4];
    const int t = threadIdx.x;
    const int b = blockIdx.x;
    const int i = b * 256 + t;
    const int lane = t & 63;
    const int wid = t >> 6;
    int v = (i < N) ? deg[i] : 0;
    int x = v;
    #pragma unroll
    for (int o = 1; o < 64; o <<= 1) {
        int y = __shfl_up(x, o, 64);
        if (lane >= o) x += y;
    }
    if (lane == 63) ws[wid] = x;
    __syncthreads();
    int prefix = (b > 0) ? bsum[b - 1] : 0;
    for (int k = 0; k < wid; ++k) prefix += ws[k];
    if (i < N) {
        row_ptr[i + 1] = prefix + x;
        cursor[i] = prefix + x - v;
    }
    if (i == 0) row_ptr[0] = 0;
}

// ---------------------------------------------------------------- MFMA GEMM body (+ fused el/er extra tile)
// el -> packed fp16 elh table (consumed by the wk alpha kernels, never by gathers).
// EMBED (layer2): pad slot h*48+47 zeroed.
template <int TT, int NLOG, int OSTRIDE, bool EMBED, bool GATHER, typename AT>
__device__ __forceinline__ void gemm_body(
    int bx,
    const AT* __restrict__ A, const __half* __restrict__ Wt,
    __half* __restrict__ C, __half* __restrict__ elh, float* __restrict__ er,
    const int* __restrict__ gather, int N) {
    constexpr int LDA = 136;
    __shared__ _Float16 As[64 * LDA];
    __shared__ int ridx[64];
    const int tid = threadIdx.x;
    const int r0 = bx * 64;

    if (tid < 64) {
        int row = r0 + tid;
        int pr = 0;
        if (row < N) pr = GATHER ? gather[row] : row;
        ridx[tid] = pr;
    }
    __syncthreads();

    {
        const int r = tid >> 2, q = tid & 3;
        const int src = ridx[r];
        if constexpr (std::is_same<AT, float>::value) {
            const float4* A4 = (const float4*)A;
            #pragma unroll
            for (int i = 0; i < 8; ++i) {
                float4 v = A4[(size_t)src * 32 + q * 8 + i];
                half4_t hv = {(_Float16)v.x, (_Float16)v.y, (_Float16)v.z, (_Float16)v.w};
                *(half4_t*)&As[r * LDA + q * 32 + i * 4] = hv;
            }
        } else {
            const uint4* A4 = (const uint4*)A;
            #pragma unroll
            for (int i = 0; i < 4; ++i) {
                uint4 v = A4[(size_t)src * 16 + q * 4 + i];
                *(uint4*)&As[r * LDA + q * 32 + i * 8] = v;
            }
        }
    }
    __syncthreads();

    const int lane = tid & 63;
    const int wave = tid >> 6;
    const int col = lane & 15;
    const int quad = lane >> 4;
    const int arow = wave * 16 + col;

    floatx4 acc[TT];
    #pragma unroll
    for (int t = 0; t < TT; ++t) acc[t] = (floatx4){0.f, 0.f, 0.f, 0.f};

    #pragma unroll
    for (int kc = 0; kc < 4; ++kc) {
        half8_t a = *(const half8_t*)&As[arow * LDA + kc * 32 + quad * 8];
        #pragma unroll
        for (int t = 0; t < TT; ++t) {
            half8_t b = *(const half8_t*)&Wt[(size_t)(t * 16 + col) * 128 + kc * 32 + quad * 8];
            acc[t] = __builtin_amdgcn_mfma_f32_16x16x32_f16(a, b, acc[t], 0, 0, 0);
        }
    }

    #pragma unroll
    for (int t = 0; t < TT - 1; ++t) {
        #pragma unroll
        for (int r = 0; r < 4; ++r) {
            int row = r0 + wave * 16 + quad * 4 + r;
            int c = t * 16 + col;
            if (row < N && c < NLOG) {
                int sc = EMBED ? (c + c / 47) : c;   // per-head pad: storage col = h*48+d
                C[(size_t)row * OSTRIDE + sc] = __float2half(acc[t][r]);
            }
        }
    }
    // extra tile -> el/er
    #pragma unroll
    for (int r = 0; r < 4; ++r) {
        int row = r0 + wave * 16 + quad * 4 + r;
        if (row < N) {
            if (col < 4) {
                elh[row * 4 + col] = __float2half(acc[TT - 1][r]);
                if constexpr (EMBED)
                    C[(size_t)row * OSTRIDE + col * 48 + 47] = __float2half(0.f);
            } else if (col < 8) {
                er[row * 4 + (col - 4)] = acc[TT - 1][r];
            }
        }
    }
}

template <int TT, int NLOG, int OSTRIDE, bool EMBED, bool GATHER, typename AT>
__global__ __launch_bounds__(256) void gemm_mfma(
    const AT* __restrict__ A, const __half* __restrict__ Wt,
    __half* __restrict__ C, __half* __restrict__ elh, float* __restrict__ er,
    const int* __restrict__ gather, int N) {
    gemm_body<TT, NLOG, OSTRIDE, EMBED, GATHER, AT>(blockIdx.x, A, Wt, C, elh, er, gather, N);
}

// ---------------------------------------------------------------- fused scatter + layer-1 GEMM (R2, best measured)
__global__ __launch_bounds__(256) void scatter_gemm1(
    const int* __restrict__ src, const int* __restrict__ dst,
    int* __restrict__ cursor, int* __restrict__ e_src, int E,
    const float* __restrict__ A, const __half* __restrict__ Wt,
    __half* __restrict__ C, __half* __restrict__ elh, float* __restrict__ er, int N) {
    const int g = blockIdx.x >> 3;
    if ((g & 1) == 0) {
        const int part = blockIdx.x & 7;
        const int sb = g >> 1;                    // 0..199
        const int psz = N_NODES / 8;              // 12500
        const int lo = part * psz;
        const int hi = lo + psz;
        const int SLICE = E / 200;                // 8000 (exact)
        const int4* d4 = (const int4*)(dst + sb * SLICE);
        const int4* s4 = (const int4*)(src + sb * SLICE);
        const int nvec = SLICE / 4;               // 2000
        for (int v = threadIdx.x; v < nvec; v += 256) {
            int4 dd = d4[v];
            int4 ss = s4[v];
            if (dd.x >= lo && dd.x < hi) e_src[atomicAdd(&cursor[dd.x], 1)] = ss.x;
            if (dd.y >= lo && dd.y < hi) e_src[atomicAdd(&cursor[dd.y], 1)] = ss.y;
            if (dd.z >= lo && dd.z < hi) e_src[atomicAdd(&cursor[dd.z], 1)] = ss.z;
            if (dd.w >= lo && dd.w < hi) e_src[atomicAdd(&cursor[dd.w], 1)] = ss.w;
        }
    } else {
        const int bx = (g >> 1) * 8 + (blockIdx.x & 7);   // 0..1599
        if (bx * 64 < N)
            gemm_body<9, 128, 128, false, false, float>(bx, A, Wt, C, elh, er, nullptr, N);
    }
}

// ---------------------------------------------------------------- normalized-alpha precompute
// One wave per node; lane = (head h = lane>>4, slot e = lane&15).
// Pass 1: accumulate softmax denominator s per (node,head); 16-lane butterfly reduce.
// Pass 2: write alpha = w/s to plane layout wbuf[h*E + i] (fp32, 64B-coalesced).
// Moves ALL weight math (exp chain + random elh loads + normalization) off the
// gathers' critical path into a tiny kernel where elh stays L2-resident.
__global__ __launch_bounds__(256) void wk_alpha(
    const __half* __restrict__ elh, const float* __restrict__ er,
    const int* __restrict__ row_ptr, const int* __restrict__ e_src,
    float* __restrict__ wbuf) {
    const int n = blockIdx.x * 4 + (threadIdx.x >> 6);
    const int lane = threadIdx.x & 63;
    const int h = lane >> 4;
    const int e = lane & 15;
    const int start = row_ptr[n], end = row_ptr[n + 1];
    const float ern = er[n * 4 + h];
    float s = 0.f;
    for (int i = start + e; i < end; i += 16) {
        int sv = e_src[i];
        float x = __half2float(elh[sv * 4 + h]) + ern;
        s += exp2f(fmaxf(x, 0.2f * x));
    }
    #pragma unroll
    for (int o = 1; o < 16; o <<= 1) s += __shfl_xor(s, o, 64);
    const float inv = 1.f / fmaxf(s, 1e-9f);
    float* wp = wbuf + h * N_EDGES;
    for (int i = start + e; i < end; i += 16) {
        int sv = e_src[i];
        float x = __half2float(elh[sv * 4 + h]) + ern;
        wp[i] = exp2f(fmaxf(x, 0.2f * x)) * inv;
    }
}

// ---------------------------------------------------------------- layer-1 gather (alpha precomputed)
// Per 4-edge group: 1 float4 broadcast alpha load (address = f(i) only, issues at
// loop top, independent of sv/feature chain) + 4 sv + 4 feature loads + 8 FMA.
// No exp, no elh, no s-accumulation, no divide.
__global__ __launch_bounds__(256) void gat_gather1(
    const __half* __restrict__ feat, const float* __restrict__ wbuf,
    const int* __restrict__ row_ptr, const int* __restrict__ e_src,
    const float* __restrict__ bias, __half* __restrict__ out) {
    const int t = threadIdx.x;
    const int lane = t & 63;
    const int n = blockIdx.x * 4 + (t >> 6);
    const int h = lane >> 4;
    const int start = row_ptr[n], end = row_ptr[n + 1];
    const char* fb = (const char*)feat;
    const uint32_t flo = (uint32_t)lane * 4u;
    const float* wp = wbuf + h * N_EDGES;
    float ax = 0.f, ay = 0.f;
    int i = start;
    int pre = (4 - (start & 3)) & 3;          // align i to 4 for float4 alpha loads
    if (pre > end - start) pre = end - start;
    for (int k = 0; k < pre; ++k, ++i) {
        int sv = e_src[i];
        float ww = wp[i];
        float2 g = __half22float2(*(const __half2*)(fb + (uint32_t)sv * 256u + flo));
        ax += ww * g.x;
        ay += ww * g.y;
    }
    for (; i + 4 <= end; i += 4) {
        float4 w = *(const float4*)(wp + i);
        int sv0 = e_src[i + 0], sv1 = e_src[i + 1], sv2 = e_src[i + 2], sv3 = e_src[i + 3];
        __half2 f0 = *(const __half2*)(fb + (uint32_t)sv0 * 256u + flo);
        __half2 f1 = *(const __half2*)(fb + (uint32_t)sv1 * 256u + flo);
        __half2 f2v = *(const __half2*)(fb + (uint32_t)sv2 * 256u + flo);
        __half2 f3 = *(const __half2*)(fb + (uint32_t)sv3 * 256u + flo);
        float2 g0 = __half22float2(f0), g1 = __half22float2(f1);
        float2 g2 = __half22float2(f2v), g3 = __half22float2(f3);
        ax += w.x * g0.x + w.y * g1.x + w.z * g2.x + w.w * g3.x;
        ay += w.x * g0.y + w.y * g1.y + w.z * g2.y + w.w * g3.y;
    }
    for (; i < end; ++i) {
        int sv = e_src[i];
        float ww = wp[i];
        float2 g = __half22float2(*(const __half2*)(fb + (uint32_t)sv * 256u + flo));
        ax += ww * g.x;
        ay += ww * g.y;
    }
    float ox = ax + bias[lane * 2 + 0];
    float oy = ay + bias[lane * 2 + 1];
    ox = (ox > 0.f) ? ox : (__expf(ox) - 1.f);
    oy = (oy > 0.f) ? oy : (__expf(oy) - 1.f);
    ((__half2*)out)[(size_t)n * 64 + lane] = __floats2half2_rn(ox, oy);
}

// ---------------------------------------------------------------- layer-2 gather (alpha precomputed)
__global__ __launch_bounds__(256) void gat_gather2(
    const __half* __restrict__ feat, const float* __restrict__ wbuf,
    const int* __restrict__ row_ptr, const int* __restrict__ e_src,
    const float* __restrict__ bias, float* __restrict__ out) {
    const int t = threadIdx.x;
    const int lane = t & 63;
    const int n = blockIdx.x * 4 + (t >> 6);
    if (lane < 48) {
        const int h = lane / 12;
        const int q = lane - h * 12;
        const int start = row_ptr[n], end = row_ptr[n + 1];
        const char* fb = (const char*)feat;
        const uint32_t flo = (uint32_t)lane * 8u;
        const float* wp = wbuf + h * N_EDGES;
        float a0 = 0.f, a1 = 0.f, a2 = 0.f, a3 = 0.f;
        int i = start;
        int pre = (4 - (start & 3)) & 3;
        if (pre > end - start) pre = end - start;
        for (int k = 0; k < pre; ++k, ++i) {
            int sv = e_src[i];
            float ww = wp[i];
            half4_t f0 = *(const half4_t*)(fb + (uint32_t)sv * 384u + flo);
            a0 += ww * (float)f0[0];
            a1 += ww * (float)f0[1];
            a2 += ww * (float)f0[2];
            a3 += ww * (float)f0[3];
        }
        for (; i + 4 <= end; i += 4) {
            float4 w = *(const float4*)(wp + i);
            int sv0 = e_src[i + 0], sv1 = e_src[i + 1], sv2 = e_src[i + 2], sv3 = e_src[i + 3];
            half4_t f0 = *(const half4_t*)(fb + (uint32_t)sv0 * 384u + flo);
            half4_t f1 = *(const half4_t*)(fb + (uint32_t)sv1 * 384u + flo);
            half4_t f2 = *(const half4_t*)(fb + (uint32_t)sv2 * 384u + flo);
            half4_t f3 = *(const half4_t*)(fb + (uint32_t)sv3 * 384u + flo);
            a0 += w.x * (float)f0[0] + w.y * (float)f1[0] + w.z * (float)f2[0] + w.w * (float)f3[0];
            a1 += w.x * (float)f0[1] + w.y * (float)f1[1] + w.z * (float)f2[1] + w.w * (float)f3[1];
            a2 += w.x * (float)f0[2] + w.y * (float)f1[2] + w.z * (float)f2[2] + w.w * (float)f3[2];
            a3 += w.x * (float)f0[3] + w.y * (float)f1[3] + w.z * (float)f2[3] + w.w * (float)f3[3];
        }
        for (; i < end; ++i) {
            int sv = e_src[i];
            float ww = wp[i];
            half4_t f0 = *(const half4_t*)(fb + (uint32_t)sv * 384u + flo);
            a0 += ww * (float)f0[0];
            a1 += ww * (float)f0[1];
            a2 += ww * (float)f0[2];
            a3 += ww * (float)f0[3];
        }
        if (q == 11) a3 = 0.f;               // pad col safety (pad is 0 in feat2)
        const int d0 = q * 4;
        float b0 = bias[h * 47 + d0 + 0];
        float b1 = bias[h * 47 + d0 + 1];
        float b2 = bias[h * 47 + d0 + 2];
        float b3 = (d0 + 3 < 47) ? bias[h * 47 + d0 + 3] : 0.f;
        float r0 = a0 + b0;
        float r1 = a1 + b1;
        float r2 = a2 + b2;
        float r3 = a3 + b3;
        float t0 = r0 + __shfl(r0, lane + 12, 64) + __shfl(r0, lane + 24, 64) + __shfl(r0, lane + 36, 64);
        float t1 = r1 + __shfl(r1, lane + 12, 64) + __shfl(r1, lane + 24, 64) + __shfl(r1, lane + 36, 64);
        float t2 = r2 + __shfl(r2, lane + 12, 64) + __shfl(r2, lane + 24, 64) + __shfl(r2, lane + 36, 64);
        float t3 = r3 + __shfl(r3, lane + 12, 64) + __shfl(r3, lane + 24, 64) + __shfl(r3, lane + 36, 64);
        if (h == 0) {
            size_t base = (size_t)n * 47 + d0;
            out[base + 0] = 0.25f * t0;
            out[base + 1] = 0.25f * t1;
            out[base + 2] = 0.25f * t2;
            if (d0 + 3 < 47) out[base + 3] = 0.25f * t3;
        }
    }
}

// ---------------------------------------------------------------- launcher
extern "C" void kernel_launch(void* const* d_in, const int* in_sizes, int n_in,
                              void* d_out, int out_size, void* d_ws, size_t ws_size,
                              hipStream_t stream) {
    const int N = N_NODES, E = N_EDGES;
    const float* x    = (const float*)d_in[0];
    const int*   src  = (const int*)d_in[1];
    const int*   dst  = (const int*)d_in[2];
    const int*   inv  = (const int*)d_in[3];
    const float* W1   = (const float*)d_in[4];
    const float* al1  = (const float*)d_in[5];
    const float* ar1  = (const float*)d_in[6];
    const float* b1   = (const float*)d_in[7];
    const float* W2   = (const float*)d_in[8];
    const float* al2  = (const float*)d_in[9];
    const float* ar2  = (const float*)d_in[10];
    const float* b2   = (const float*)d_in[11];
    float* out = (float*)d_out;

    char* p = (char*)d_ws;
    auto carve = [&](size_t bytes) {
        char* q = p;
        p += (bytes + 255) & ~size_t(255);
        return q;
    };
    __half* feat1   = (__half*)carve((size_t)N * 128 * 2);
    __half* feat2   = (__half*)carve((size_t)N * 192 * 2);  // padded h*48+d; pad slot h*48+47 = 0
    __half* hbuf    = (__half*)carve((size_t)N * 128 * 2);
    __half* Wt1     = (__half*)carve(144 * 128 * 2);
    __half* Wt2     = (__half*)carve(208 * 128 * 2);
    __half* elh1    = (__half*)carve((size_t)N * 4 * 2);
    __half* elh2    = (__half*)carve((size_t)N * 4 * 2);
    float*  er      = (float*)carve((size_t)N * 4 * 4);
    int*    deg     = (int*)carve((size_t)N * 4);
    int*    row_ptr = (int*)carve((size_t)(N + 1) * 4);
    int*    cursor  = (int*)carve((size_t)N * 4);
    int*    bsum    = (int*)carve(512 * 4);
    int*    e_src   = (int*)carve((size_t)E * 4);
    float*  wbuf    = (float*)carve((size_t)4 * E * 4);    // alpha planes, reused layer1/layer2

    const int nb = (N + 255) / 256;  // 391

    // ---- CSR build + weight prep (R2 schedule: fused count+prep) ----
    hipMemsetAsync(deg, 0, (size_t)N * 4, stream);
    csr_prep<<<6250 + 352, 256, 0, stream>>>(dst, deg, E, W1, W2, al1, ar1, al2, ar2, Wt1, Wt2);
    block_sums<<<nb, 256, 0, stream>>>(deg, bsum, N);
    scan_bsum<<<1, 512, 0, stream>>>(bsum, nb);
    scan_final<<<nb, 256, 0, stream>>>(deg, bsum, row_ptr, cursor, N);

    // ---- fused scatter + layer-1 GEMM (R2, best measured) ----
    scatter_gemm1<<<3200, 256, 0, stream>>>(src, dst, cursor, e_src, E,
                                            x, Wt1, feat1, elh1, er, N);

    // ---- layer 1: alpha precompute + aggregate ----
    wk_alpha<<<N / 4, 256, 0, stream>>>(elh1, er, row_ptr, e_src, wbuf);
    gat_gather1<<<(N + 3) / 4, 256, 0, stream>>>(feat1, wbuf, row_ptr, e_src, b1, hbuf);

    // ---- layer 2: GEMM (gathered via inverse_idx) + alpha + aggregate ----
    gemm_mfma<13, 188, 192, true, true, __half><<<(N + 63) / 64, 256, 0, stream>>>(
        hbuf, Wt2, feat2, elh2, er, inv, N);
    wk_alpha<<<N / 4, 256, 0, stream>>>(elh2, er, row_ptr, e_src, wbuf);
    gat_gather2<<<(N + 3) / 4, 256, 0, stream>>>(feat2, wbuf, row_ptr, e_src, b2, out);
}

// Round 10
// 564.153 us; speedup vs baseline: 1.0478x; 1.0478x over previous
//
#include <hip/hip_runtime.h>
#include <hip/hip_bf16.h>
#include <hip/hip_fp16.h>
#include <type_traits>

#define N_NODES 100000
#define N_EDGES 1600000
#define LOG2E 1.44269504f

typedef _Float16 half8_t __attribute__((ext_vector_type(8)));
typedef _Float16 half4_t __attribute__((ext_vector_type(4)));
typedef float floatx4 __attribute__((ext_vector_type(4)));
typedef int intx4 __attribute__((ext_vector_type(4)));
typedef unsigned int uintx4 __attribute__((ext_vector_type(4)));

// ---------------------------------------------------------------- fused count_deg + prep_w  (R2 schedule, best measured 497)
// blocks 0..6249: degree histogram.  blocks 6250..6601: weight transpose/pack.
// Wt1: 144 rows x 128. rows 0..127 = W1^T; 128..131 = W1·al1·log2e; 132..135 = W1·ar1·log2e; 136..143 = 0.
// Wt2: 208 rows x 128. rows 0..187 = W2^T; 188..191 = 0; 192..195 = W2·al2·log2e; 196..199 = W2·ar2·log2e.
// log2e bake: exp(max(e,0.2e)) == exp2(max(e',0.2e')), e' = e*log2e (verified safe R3/R4/R6/R8).
__global__ void csr_prep(const int* __restrict__ dst, int* __restrict__ deg, int E,
                         const float* __restrict__ W1, const float* __restrict__ W2,
                         const float* __restrict__ al1, const float* __restrict__ ar1,
                         const float* __restrict__ al2, const float* __restrict__ ar2,
                         __half* __restrict__ Wt1, __half* __restrict__ Wt2) {
    const int b = blockIdx.x;
    if (b < 6250) {
        int i = b * 256 + threadIdx.x;
        if (i < E) atomicAdd(&deg[__builtin_nontemporal_load(dst + i)], 1);
        return;
    }
    const int c = b - 6250;           // 0..351
    const int k = threadIdx.x;
    if (k >= 128) return;
    if (c < 128) {
        Wt1[c * 128 + k] = __float2half(W1[k * 128 + c]);
    } else if (c < 144) {
        int j = c - 128;
        float v = 0.f;
        if (j < 8) {
            int h = j & 3;
            const float* a = (j < 4) ? al1 : ar1;
            for (int d = 0; d < 32; ++d)
                v = fmaf(W1[k * 128 + h * 32 + d], a[h * 32 + d], v);
        }
        Wt1[c * 128 + k] = __float2half(v * LOG2E);
    } else if (c < 336) {
        int c2 = c - 144;  // 0..191
        float v = (c2 < 188) ? W2[k * 188 + c2] : 0.f;
        Wt2[c2 * 128 + k] = __float2half(v);
    } else {
        int j = c - 336;   // 0..15 -> Wt2 rows 192..207
        float v = 0.f;
        if (j < 8) {
            int h = j & 3;
            const float* a = (j < 4) ? al2 : ar2;
            for (int d = 0; d < 47; ++d)
                v = fmaf(W2[k * 188 + h * 47 + d], a[h * 47 + d], v);
        }
        Wt2[(192 + j) * 128 + k] = __float2half(v * LOG2E);
    }
}

__global__ void block_sums(const int* __restrict__ deg, int* __restrict__ bsum, int N) {
    __shared__ int ws[4];
    const int t = threadIdx.x;
    int i = blockIdx.x * 256 + t;
    int v = (i < N) ? deg[i] : 0;
    #pragma unroll
    for (int o = 32; o; o >>= 1) v += __shfl_down(v, o, 64);
    if ((t & 63) == 0) ws[t >> 6] = v;
    __syncthreads();
    if (t == 0) bsum[blockIdx.x] = ws[0] + ws[1] + ws[2] + ws[3];
}

__global__ void scan_bsum(int* __restrict__ bsum, int nb) {
    __shared__ int sh[512];
    const int t = threadIdx.x;
    sh[t] = (t < nb) ? bsum[t] : 0;
    __syncthreads();
    for (int o = 1; o < 512; o <<= 1) {
        int v = (t >= o) ? sh[t - o] : 0;
        __syncthreads();
        sh[t] += v;
        __syncthreads();
    }
    if (t < nb) bsum[t] = sh[t];
}

__global__ void scan_final(const int* __restrict__ deg, const int* __restrict__ bsum,
                           int* __restrict__ row_ptr, int* __restrict__ cursor, int N) {
    __shared__ int ws[4];
    const int t = threadIdx.x;
    const int b = blockIdx.x;
    const int i = b * 256 + t;
    const int lane = t & 63;
    const int wid = t >> 6;
    int v = (i < N) ? deg[i] : 0;
    int x = v;
    #pragma unroll
    for (int o = 1; o < 64; o <<= 1) {
        int y = __shfl_up(x, o, 64);
        if (lane >= o) x += y;
    }
    if (lane == 63) ws[wid] = x;
    __syncthreads();
    int prefix = (b > 0) ? bsum[b - 1] : 0;
    for (int k = 0; k < wid; ++k) prefix += ws[k];
    if (i < N) {
        row_ptr[i + 1] = prefix + x;
        cursor[i] = prefix + x - v;
    }
    if (i == 0) row_ptr[0] = 0;
}

// ---------------------------------------------------------------- MFMA GEMM body (+ fused el/er extra tile)
// A-tile loads are NONTEMPORAL (ext_vector types for the builtin): each input row
// is read exactly once chip-wide; skipping L2 allocation stops them evicting
// e_src write lines (the R3-measured 17x write amplification) and feat rows.
// EMBED (layer2): el -> feat pad slot h*48+47 (rides the row's cache lines;
// R6 ledger: separate table costs +30MB FETCH).  else: el -> packed elh1 table.
template <int TT, int NLOG, int OSTRIDE, bool EMBED, bool GATHER, typename AT>
__device__ __forceinline__ void gemm_body(
    int bx,
    const AT* __restrict__ A, const __half* __restrict__ Wt,
    __half* __restrict__ C, __half* __restrict__ elh, float* __restrict__ er,
    const int* __restrict__ gather, int N) {
    constexpr int LDA = 136;
    __shared__ _Float16 As[64 * LDA];
    __shared__ int ridx[64];
    const int tid = threadIdx.x;
    const int r0 = bx * 64;

    if (tid < 64) {
        int row = r0 + tid;
        int pr = 0;
        if (row < N) pr = GATHER ? gather[row] : row;
        ridx[tid] = pr;
    }
    __syncthreads();

    {
        const int r = tid >> 2, q = tid & 3;
        const int src = ridx[r];
        if constexpr (std::is_same<AT, float>::value) {
            const floatx4* A4 = (const floatx4*)A;
            #pragma unroll
            for (int i = 0; i < 8; ++i) {
                floatx4 v = __builtin_nontemporal_load(&A4[(size_t)src * 32 + q * 8 + i]);
                half4_t hv = {(_Float16)v.x, (_Float16)v.y, (_Float16)v.z, (_Float16)v.w};
                *(half4_t*)&As[r * LDA + q * 32 + i * 4] = hv;
            }
        } else {
            const uintx4* A4 = (const uintx4*)A;
            #pragma unroll
            for (int i = 0; i < 4; ++i) {
                uintx4 v = __builtin_nontemporal_load(&A4[(size_t)src * 16 + q * 4 + i]);
                *(uintx4*)&As[r * LDA + q * 32 + i * 8] = v;
            }
        }
    }
    __syncthreads();

    const int lane = tid & 63;
    const int wave = tid >> 6;
    const int col = lane & 15;
    const int quad = lane >> 4;
    const int arow = wave * 16 + col;

    floatx4 acc[TT];
    #pragma unroll
    for (int t = 0; t < TT; ++t) acc[t] = (floatx4){0.f, 0.f, 0.f, 0.f};

    #pragma unroll
    for (int kc = 0; kc < 4; ++kc) {
        half8_t a = *(const half8_t*)&As[arow * LDA + kc * 32 + quad * 8];
        #pragma unroll
        for (int t = 0; t < TT; ++t) {
            half8_t b = *(const half8_t*)&Wt[(size_t)(t * 16 + col) * 128 + kc * 32 + quad * 8];
            acc[t] = __builtin_amdgcn_mfma_f32_16x16x32_f16(a, b, acc[t], 0, 0, 0);
        }
    }

    #pragma unroll
    for (int t = 0; t < TT - 1; ++t) {
        #pragma unroll
        for (int r = 0; r < 4; ++r) {
            int row = r0 + wave * 16 + quad * 4 + r;
            int c = t * 16 + col;
            if (row < N && c < NLOG) {
                int sc = EMBED ? (c + c / 47) : c;   // per-head pad: storage col = h*48+d
                C[(size_t)row * OSTRIDE + sc] = __float2half(acc[t][r]);
            }
        }
    }
    // extra tile -> el/er
    #pragma unroll
    for (int r = 0; r < 4; ++r) {
        int row = r0 + wave * 16 + quad * 4 + r;
        if (row < N) {
            if (col < 4) {
                if constexpr (EMBED)
                    C[(size_t)row * OSTRIDE + col * 48 + 47] = __float2half(acc[TT - 1][r]);
                else
                    elh[row * 4 + col] = __float2half(acc[TT - 1][r]);
            } else if (col < 8) {
                er[row * 4 + (col - 4)] = acc[TT - 1][r];
            }
        }
    }
}

template <int TT, int NLOG, int OSTRIDE, bool EMBED, bool GATHER, typename AT>
__global__ __launch_bounds__(256) void gemm_mfma(
    const AT* __restrict__ A, const __half* __restrict__ Wt,
    __half* __restrict__ C, __half* __restrict__ elh, float* __restrict__ er,
    const int* __restrict__ gather, int N) {
    gemm_body<TT, NLOG, OSTRIDE, EMBED, GATHER, AT>(blockIdx.x, A, Wt, C, elh, er, gather, N);
}

// ---------------------------------------------------------------- fused scatter + layer-1 GEMM (R2, best measured)
// dst/src edge loads nontemporal (pure stream) -- keeps L2 for e_src write lines.
__global__ __launch_bounds__(256) void scatter_gemm1(
    const int* __restrict__ src, const int* __restrict__ dst,
    int* __restrict__ cursor, int* __restrict__ e_src, int E,
    const float* __restrict__ A, const __half* __restrict__ Wt,
    __half* __restrict__ C, __half* __restrict__ elh, float* __restrict__ er, int N) {
    const int g = blockIdx.x >> 3;
    if ((g & 1) == 0) {
        const int part = blockIdx.x & 7;
        const int sb = g >> 1;                    // 0..199
        const int psz = N_NODES / 8;              // 12500
        const int lo = part * psz;
        const int hi = lo + psz;
        const int SLICE = E / 200;                // 8000 (exact)
        const intx4* d4 = (const intx4*)(dst + sb * SLICE);
        const intx4* s4 = (const intx4*)(src + sb * SLICE);
        const int nvec = SLICE / 4;               // 2000
        for (int v = threadIdx.x; v < nvec; v += 256) {
            intx4 dd = __builtin_nontemporal_load(&d4[v]);
            intx4 ss = __builtin_nontemporal_load(&s4[v]);
            if (dd.x >= lo && dd.x < hi) e_src[atomicAdd(&cursor[dd.x], 1)] = ss.x;
            if (dd.y >= lo && dd.y < hi) e_src[atomicAdd(&cursor[dd.y], 1)] = ss.y;
            if (dd.z >= lo && dd.z < hi) e_src[atomicAdd(&cursor[dd.z], 1)] = ss.z;
            if (dd.w >= lo && dd.w < hi) e_src[atomicAdd(&cursor[dd.w], 1)] = ss.w;
        }
    } else {
        const int bx = (g >> 1) * 8 + (blockIdx.x & 7);   // 0..1599
        if (bx * 64 < N)
            gemm_body<9, 128, 128, false, false, float>(bx, A, Wt, C, elh, er, nullptr, N);
    }
}

// ---------------------------------------------------------------- layer-1 gather
// 4-wide flat loop (proven optimum: R3 pipeline, R4 8-wide, R8 alpha-precompute
// all regressed).  e_src loads nontemporal (read-once stream, frees L2 for feat).
__global__ __launch_bounds__(256) void gat_gather1(
    const __half* __restrict__ feat, const __half* __restrict__ elh,
    const float* __restrict__ er,
    const int* __restrict__ row_ptr, const int* __restrict__ e_src,
    const float* __restrict__ bias, __half* __restrict__ out) {
    const int t = threadIdx.x;
    const int lane = t & 63;
    const int n = blockIdx.x * 4 + (t >> 6);
    const int h = lane >> 4;
    const int start = row_ptr[n], end = row_ptr[n + 1];
    const char* fb = (const char*)feat;
    const uint32_t flo = (uint32_t)lane * 4u;
    const float ern = er[n * 4 + h];
    float ax = 0.f, ay = 0.f, s = 0.f;
    int i = start;
    for (; i + 4 <= end; i += 4) {
        int sv0 = __builtin_nontemporal_load(e_src + i + 0);
        int sv1 = __builtin_nontemporal_load(e_src + i + 1);
        int sv2 = __builtin_nontemporal_load(e_src + i + 2);
        int sv3 = __builtin_nontemporal_load(e_src + i + 3);
        float e0 = __half2float(elh[sv0 * 4 + h]) + ern;
        float e1 = __half2float(elh[sv1 * 4 + h]) + ern;
        float e2 = __half2float(elh[sv2 * 4 + h]) + ern;
        float e3 = __half2float(elh[sv3 * 4 + h]) + ern;
        float w0 = exp2f(fmaxf(e0, 0.2f * e0));
        float w1 = exp2f(fmaxf(e1, 0.2f * e1));
        float w2 = exp2f(fmaxf(e2, 0.2f * e2));
        float w3 = exp2f(fmaxf(e3, 0.2f * e3));
        __half2 f0 = *(const __half2*)(fb + (uint32_t)sv0 * 256u + flo);
        __half2 f1 = *(const __half2*)(fb + (uint32_t)sv1 * 256u + flo);
        __half2 f2v = *(const __half2*)(fb + (uint32_t)sv2 * 256u + flo);
        __half2 f3 = *(const __half2*)(fb + (uint32_t)sv3 * 256u + flo);
        float2 g0 = __half22float2(f0), g1 = __half22float2(f1);
        float2 g2 = __half22float2(f2v), g3 = __half22float2(f3);
        s += (w0 + w1) + (w2 + w3);
        ax += w0 * g0.x + w1 * g1.x + w2 * g2.x + w3 * g3.x;
        ay += w0 * g0.y + w1 * g1.y + w2 * g2.y + w3 * g3.y;
    }
    for (; i < end; ++i) {
        int sv = e_src[i];
        float e = __half2float(elh[sv * 4 + h]) + ern;
        float ww = exp2f(fmaxf(e, 0.2f * e));
        float2 g = __half22float2(*(const __half2*)(fb + (uint32_t)sv * 256u + flo));
        s += ww;
        ax += ww * g.x;
        ay += ww * g.y;
    }
    float inv = 1.f / fmaxf(s, 1e-9f);
    float ox = ax * inv + bias[lane * 2 + 0];
    float oy = ay * inv + bias[lane * 2 + 1];
    ox = (ox > 0.f) ? ox : (__expf(ox) - 1.f);
    oy = (oy > 0.f) ? oy : (__expf(oy) - 1.f);
    ((__half2*)out)[(size_t)n * 64 + lane] = __floats2half2_rn(ox, oy);
}

// ---------------------------------------------------------------- layer-2 gather (el embedded in feat pad slots)
// R2-measured optimum structure: el2 rides the feature row's cache lines (pad slot
// h*48+47), extracted via one shfl per edge from lane g11's f[3].  Failed-variant
// ledger: R1 lane-restructure (120), R3 pipeline (105.8), R4 8-wide (102.8),
// R6 elh2 table (110.6, +30MB FETCH), R8 alpha-precompute (VALU 41% but dur flat
// -> FETCH-BOUND at ~3 TB/s; 278MB = 8 XCD x 38MB feat2 duplication, structural).
__global__ __launch_bounds__(256) void gat_gather2(
    const __half* __restrict__ feat, const float* __restrict__ er,
    const int* __restrict__ row_ptr, const int* __restrict__ e_src,
    const float* __restrict__ bias, float* __restrict__ out) {
    const int t = threadIdx.x;
    const int lane = t & 63;
    const int n = blockIdx.x * 4 + (t >> 6);
    if (lane < 48) {
        const int h = lane / 12;
        const int q = lane - h * 12;
        const int g11 = h * 12 + 11;         // lane holding el_h in f[3]
        const int start = row_ptr[n], end = row_ptr[n + 1];
        const char* fb = (const char*)feat;
        const uint32_t flo = (uint32_t)lane * 8u;
        const float ern = er[n * 4 + h];
        float a0 = 0.f, a1 = 0.f, a2 = 0.f, a3 = 0.f, s = 0.f;
        int i = start;
        for (; i + 4 <= end; i += 4) {
            int sv0 = __builtin_nontemporal_load(e_src + i + 0);
            int sv1 = __builtin_nontemporal_load(e_src + i + 1);
            int sv2 = __builtin_nontemporal_load(e_src + i + 2);
            int sv3 = __builtin_nontemporal_load(e_src + i + 3);
            half4_t f0 = *(const half4_t*)(fb + (uint32_t)sv0 * 384u + flo);
            half4_t f1 = *(const half4_t*)(fb + (uint32_t)sv1 * 384u + flo);
            half4_t f2 = *(const half4_t*)(fb + (uint32_t)sv2 * 384u + flo);
            half4_t f3 = *(const half4_t*)(fb + (uint32_t)sv3 * 384u + flo);
            float e0 = __shfl((float)f0[3], g11, 64) + ern;
            float e1 = __shfl((float)f1[3], g11, 64) + ern;
            float e2 = __shfl((float)f2[3], g11, 64) + ern;
            float e3 = __shfl((float)f3[3], g11, 64) + ern;
            float w0 = exp2f(fmaxf(e0, 0.2f * e0));
            float w1 = exp2f(fmaxf(e1, 0.2f * e1));
            float w2 = exp2f(fmaxf(e2, 0.2f * e2));
            float w3 = exp2f(fmaxf(e3, 0.2f * e3));
            s += (w0 + w1) + (w2 + w3);
            a0 += w0 * (float)f0[0] + w1 * (float)f1[0] + w2 * (float)f2[0] + w3 * (float)f3[0];
            a1 += w0 * (float)f0[1] + w1 * (float)f1[1] + w2 * (float)f2[1] + w3 * (float)f3[1];
            a2 += w0 * (float)f0[2] + w1 * (float)f1[2] + w2 * (float)f2[2] + w3 * (float)f3[2];
            a3 += w0 * (float)f0[3] + w1 * (float)f1[3] + w2 * (float)f2[3] + w3 * (float)f3[3];
        }
        for (; i < end; ++i) {
            int sv = e_src[i];
            half4_t f0 = *(const half4_t*)(fb + (uint32_t)sv * 384u + flo);
            float e = __shfl((float)f0[3], g11, 64) + ern;
            float ww = exp2f(fmaxf(e, 0.2f * e));
            s += ww;
            a0 += ww * (float)f0[0];
            a1 += ww * (float)f0[1];
            a2 += ww * (float)f0[2];
            a3 += ww * (float)f0[3];
        }
        if (q == 11) a3 = 0.f;               // pad col (holds el) — mask from accumulator
        float inv = 1.f / fmaxf(s, 1e-9f);
        const int d0 = q * 4;
        float b0 = bias[h * 47 + d0 + 0];
        float b1 = bias[h * 47 + d0 + 1];
        float b2 = bias[h * 47 + d0 + 2];
        float b3 = (d0 + 3 < 47) ? bias[h * 47 + d0 + 3] : 0.f;
        float r0 = a0 * inv + b0;
        float r1 = a1 * inv + b1;
        float r2 = a2 * inv + b2;
        float r3 = a3 * inv + b3;
        float t0 = r0 + __shfl(r0, lane + 12, 64) + __shfl(r0, lane + 24, 64) + __shfl(r0, lane + 36, 64);
        float t1 = r1 + __shfl(r1, lane + 12, 64) + __shfl(r1, lane + 24, 64) + __shfl(r1, lane + 36, 64);
        float t2 = r2 + __shfl(r2, lane + 12, 64) + __shfl(r2, lane + 24, 64) + __shfl(r2, lane + 36, 64);
        float t3 = r3 + __shfl(r3, lane + 12, 64) + __shfl(r3, lane + 24, 64) + __shfl(r3, lane + 36, 64);
        if (h == 0) {
            size_t base = (size_t)n * 47 + d0;
            out[base + 0] = 0.25f * t0;
            out[base + 1] = 0.25f * t1;
            out[base + 2] = 0.25f * t2;
            if (d0 + 3 < 47) out[base + 3] = 0.25f * t3;
        }
    }
}

// ---------------------------------------------------------------- launcher (R2 schedule, best measured)
extern "C" void kernel_launch(void* const* d_in, const int* in_sizes, int n_in,
                              void* d_out, int out_size, void* d_ws, size_t ws_size,
                              hipStream_t stream) {
    const int N = N_NODES, E = N_EDGES;
    const float* x    = (const float*)d_in[0];
    const int*   src  = (const int*)d_in[1];
    const int*   dst  = (const int*)d_in[2];
    const int*   inv  = (const int*)d_in[3];
    const float* W1   = (const float*)d_in[4];
    const float* al1  = (const float*)d_in[5];
    const float* ar1  = (const float*)d_in[6];
    const float* b1   = (const float*)d_in[7];
    const float* W2   = (const float*)d_in[8];
    const float* al2  = (const float*)d_in[9];
    const float* ar2  = (const float*)d_in[10];
    const float* b2   = (const float*)d_in[11];
    float* out = (float*)d_out;

    char* p = (char*)d_ws;
    auto carve = [&](size_t bytes) {
        char* q = p;
        p += (bytes + 255) & ~size_t(255);
        return q;
    };
    __half* feat1   = (__half*)carve((size_t)N * 128 * 2);
    __half* feat2   = (__half*)carve((size_t)N * 192 * 2);  // padded h*48+d; pad slot h*48+47 = el2(h) fp16
    __half* hbuf    = (__half*)carve((size_t)N * 128 * 2);
    __half* Wt1     = (__half*)carve(144 * 128 * 2);
    __half* Wt2     = (__half*)carve(208 * 128 * 2);
    __half* elh1    = (__half*)carve((size_t)N * 4 * 2);
    float*  er      = (float*)carve((size_t)N * 4 * 4);
    int*    deg     = (int*)carve((size_t)N * 4);
    int*    row_ptr = (int*)carve((size_t)(N + 1) * 4);
    int*    cursor  = (int*)carve((size_t)N * 4);
    int*    bsum    = (int*)carve(512 * 4);
    int*    e_src   = (int*)carve((size_t)E * 4);

    const int nb = (N + 255) / 256;  // 391

    // ---- CSR build + weight prep (fused count_deg + prep_w) ----
    hipMemsetAsync(deg, 0, (size_t)N * 4, stream);
    csr_prep<<<6250 + 352, 256, 0, stream>>>(dst, deg, E, W1, W2, al1, ar1, al2, ar2, Wt1, Wt2);
    block_sums<<<nb, 256, 0, stream>>>(deg, bsum, N);
    scan_bsum<<<1, 512, 0, stream>>>(bsum, nb);
    scan_final<<<nb, 256, 0, stream>>>(deg, bsum, row_ptr, cursor, N);

    // ---- fused scatter + layer-1 GEMM (independent work, co-resident) ----
    scatter_gemm1<<<3200, 256, 0, stream>>>(src, dst, cursor, e_src, E,
                                            x, Wt1, feat1, elh1, er, N);

    // ---- layer 1 aggregate ----
    gat_gather1<<<(N + 3) / 4, 256, 0, stream>>>(feat1, elh1, er, row_ptr, e_src, b1, hbuf);

    // ---- layer 2 (rows gathered through inverse_idx; el2 embedded in feat2 pad) ----
    gemm_mfma<13, 188, 192, true, true, __half><<<(N + 63) / 64, 256, 0, stream>>>(
        hbuf, Wt2, feat2, nullptr, er, inv, N);
    gat_gather2<<<(N + 3) / 4, 256, 0, stream>>>(feat2, er, row_ptr, e_src, b2, out);
}

// Round 11
// 494.658 us; speedup vs baseline: 1.1950x; 1.1405x over previous
//
#include <hip/hip_runtime.h>
#include <hip/hip_bf16.h>
#include <hip/hip_fp16.h>
#include <type_traits>

#define N_NODES 100000
#define N_EDGES 1600000

typedef _Float16 half8_t __attribute__((ext_vector_type(8)));
typedef _Float16 half4_t __attribute__((ext_vector_type(4)));
typedef float floatx4 __attribute__((ext_vector_type(4)));

// ---------------------------------------------------------------- fused count_deg + prep_w
// blocks 0..6249: degree histogram.  blocks 6250..6601: weight transpose/pack.
// Wt1: 144 rows x 128. rows 0..127 = W1^T; 128..131 = W1·al1; 132..135 = W1·ar1; 136..143 = 0.
// Wt2: 208 rows x 128. rows 0..187 = W2^T; 188..191 = 0; 192..195 = W2·al2; 196..199 = W2·ar2; 200..207 = 0.
__global__ void csr_prep(const int* __restrict__ dst, int* __restrict__ deg, int E,
                         const float* __restrict__ W1, const float* __restrict__ W2,
                         const float* __restrict__ al1, const float* __restrict__ ar1,
                         const float* __restrict__ al2, const float* __restrict__ ar2,
                         __half* __restrict__ Wt1, __half* __restrict__ Wt2) {
    const int b = blockIdx.x;
    if (b < 6250) {
        int i = b * 256 + threadIdx.x;
        if (i < E) atomicAdd(&deg[dst[i]], 1);
        return;
    }
    const int c = b - 6250;           // 0..351
    const int k = threadIdx.x;
    if (k >= 128) return;
    if (c < 128) {
        Wt1[c * 128 + k] = __float2half(W1[k * 128 + c]);
    } else if (c < 144) {
        int j = c - 128;
        float v = 0.f;
        if (j < 8) {
            int h = j & 3;
            const float* a = (j < 4) ? al1 : ar1;
            for (int d = 0; d < 32; ++d)
                v = fmaf(W1[k * 128 + h * 32 + d], a[h * 32 + d], v);
        }
        Wt1[c * 128 + k] = __float2half(v);
    } else if (c < 336) {
        int c2 = c - 144;  // 0..191
        float v = (c2 < 188) ? W2[k * 188 + c2] : 0.f;
        Wt2[c2 * 128 + k] = __float2half(v);
    } else {
        int j = c - 336;   // 0..15 -> Wt2 rows 192..207
        float v = 0.f;
        if (j < 8) {
            int h = j & 3;
            const float* a = (j < 4) ? al2 : ar2;
            for (int d = 0; d < 47; ++d)
                v = fmaf(W2[k * 188 + h * 47 + d], a[h * 47 + d], v);
        }
        Wt2[(192 + j) * 128 + k] = __float2half(v);
    }
}

__global__ void block_sums(const int* __restrict__ deg, int* __restrict__ bsum, int N) {
    __shared__ int ws[4];
    const int t = threadIdx.x;
    int i = blockIdx.x * 256 + t;
    int v = (i < N) ? deg[i] : 0;
    #pragma unroll
    for (int o = 32; o; o >>= 1) v += __shfl_down(v, o, 64);
    if ((t & 63) == 0) ws[t >> 6] = v;
    __syncthreads();
    if (t == 0) bsum[blockIdx.x] = ws[0] + ws[1] + ws[2] + ws[3];
}

__global__ void scan_bsum(int* __restrict__ bsum, int nb) {
    __shared__ int sh[512];
    const int t = threadIdx.x;
    sh[t] = (t < nb) ? bsum[t] : 0;
    __syncthreads();
    for (int o = 1; o < 512; o <<= 1) {
        int v = (t >= o) ? sh[t - o] : 0;
        __syncthreads();
        sh[t] += v;
        __syncthreads();
    }
    if (t < nb) bsum[t] = sh[t];
}

__global__ void scan_final(const int* __restrict__ deg, const int* __restrict__ bsum,
                           int* __restrict__ row_ptr, int* __restrict__ cursor, int N) {
    __shared__ int ws[4];
    const int t = threadIdx.x;
    const int b = blockIdx.x;
    const int i = b * 256 + t;
    const int lane = t & 63;
    const int wid = t >> 6;
    int v = (i < N) ? deg[i] : 0;
    int x = v;
    #pragma unroll
    for (int o = 1; o < 64; o <<= 1) {
        int y = __shfl_up(x, o, 64);
        if (lane >= o) x += y;
    }
    if (lane == 63) ws[wid] = x;
    __syncthreads();
    int prefix = (b > 0) ? bsum[b - 1] : 0;
    for (int k = 0; k < wid; ++k) prefix += ws[k];
    if (i < N) {
        row_ptr[i + 1] = prefix + x;
        cursor[i] = prefix + x - v;
    }
    if (i == 0) row_ptr[0] = 0;
}

// ---------------------------------------------------------------- MFMA GEMM body (+ fused el/er extra tile)
// TT = total tiles; last tile: cols 0..3 = el per head, cols 4..7 = er per head.
// EMBED (layer2): el stored fp16 into feat pad slots (col h*48+47).  else (layer1): el -> packed fp16 table.
template <int TT, int NLOG, int OSTRIDE, bool EMBED, bool GATHER, typename AT>
__device__ __forceinline__ void gemm_body(
    int bx,
    const AT* __restrict__ A, const __half* __restrict__ Wt,
    __half* __restrict__ C, __half* __restrict__ elh, float* __restrict__ er,
    const int* __restrict__ gather, int N) {
    constexpr int LDA = 136;
    __shared__ _Float16 As[64 * LDA];
    __shared__ int ridx[64];
    const int tid = threadIdx.x;
    const int r0 = bx * 64;

    if (tid < 64) {
        int row = r0 + tid;
        int pr = 0;
        if (row < N) pr = GATHER ? gather[row] : row;
        ridx[tid] = pr;
    }
    __syncthreads();

    {
        const int r = tid >> 2, q = tid & 3;
        const int src = ridx[r];
        if constexpr (std::is_same<AT, float>::value) {
            const float4* A4 = (const float4*)A;
            #pragma unroll
            for (int i = 0; i < 8; ++i) {
                float4 v = A4[(size_t)src * 32 + q * 8 + i];
                half4_t hv = {(_Float16)v.x, (_Float16)v.y, (_Float16)v.z, (_Float16)v.w};
                *(half4_t*)&As[r * LDA + q * 32 + i * 4] = hv;
            }
        } else {
            const uint4* A4 = (const uint4*)A;
            #pragma unroll
            for (int i = 0; i < 4; ++i) {
                uint4 v = A4[(size_t)src * 16 + q * 4 + i];
                *(uint4*)&As[r * LDA + q * 32 + i * 8] = v;
            }
        }
    }
    __syncthreads();

    const int lane = tid & 63;
    const int wave = tid >> 6;
    const int col = lane & 15;
    const int quad = lane >> 4;
    const int arow = wave * 16 + col;

    floatx4 acc[TT];
    #pragma unroll
    for (int t = 0; t < TT; ++t) acc[t] = (floatx4){0.f, 0.f, 0.f, 0.f};

    #pragma unroll
    for (int kc = 0; kc < 4; ++kc) {
        half8_t a = *(const half8_t*)&As[arow * LDA + kc * 32 + quad * 8];
        #pragma unroll
        for (int t = 0; t < TT; ++t) {
            half8_t b = *(const half8_t*)&Wt[(size_t)(t * 16 + col) * 128 + kc * 32 + quad * 8];
            acc[t] = __builtin_amdgcn_mfma_f32_16x16x32_f16(a, b, acc[t], 0, 0, 0);
        }
    }

    #pragma unroll
    for (int t = 0; t < TT - 1; ++t) {
        #pragma unroll
        for (int r = 0; r < 4; ++r) {
            int row = r0 + wave * 16 + quad * 4 + r;
            int c = t * 16 + col;
            if (row < N && c < NLOG) {
                int sc = EMBED ? (c + c / 47) : c;   // per-head pad: storage col = h*48+d
                C[(size_t)row * OSTRIDE + sc] = __float2half(acc[t][r]);
            }
        }
    }
    // extra tile -> el/er
    #pragma unroll
    for (int r = 0; r < 4; ++r) {
        int row = r0 + wave * 16 + quad * 4 + r;
        if (row < N) {
            if (col < 4) {
                if constexpr (EMBED)
                    C[(size_t)row * OSTRIDE + col * 48 + 47] = __float2half(acc[TT - 1][r]);
                else
                    elh[row * 4 + col] = __float2half(acc[TT - 1][r]);
            } else if (col < 8) {
                er[row * 4 + (col - 4)] = acc[TT - 1][r];
            }
        }
    }
}

template <int TT, int NLOG, int OSTRIDE, bool EMBED, bool GATHER, typename AT>
__global__ __launch_bounds__(256) void gemm_mfma(
    const AT* __restrict__ A, const __half* __restrict__ Wt,
    __half* __restrict__ C, __half* __restrict__ elh, float* __restrict__ er,
    const int* __restrict__ gather, int N) {
    gemm_body<TT, NLOG, OSTRIDE, EMBED, GATHER, AT>(blockIdx.x, A, Wt, C, elh, er, gather, N);
}

// ---------------------------------------------------------------- fused scatter + layer-1 GEMM
// Groups of 8 consecutive blocks alternate roles so scatter and GEMM blocks are
// co-resident (true overlap).  Scatter keeps part = blockIdx&7 == XCD id.
// Fusion is worth ~20 µs despite e_src write amplification (R2 vs R4 ledger);
// nt-hints to curb the amplification regress further (R10: 104 -> 124 µs).
__global__ __launch_bounds__(256) void scatter_gemm1(
    const int* __restrict__ src, const int* __restrict__ dst,
    int* __restrict__ cursor, int* __restrict__ e_src, int E,
    const float* __restrict__ A, const __half* __restrict__ Wt,
    __half* __restrict__ C, __half* __restrict__ elh, float* __restrict__ er, int N) {
    const int g = blockIdx.x >> 3;
    if ((g & 1) == 0) {
        // ---- scatter role ----
        const int part = blockIdx.x & 7;
        const int sb = g >> 1;                    // 0..199
        const int psz = N_NODES / 8;              // 12500
        const int lo = part * psz;
        const int hi = lo + psz;
        const int SLICE = E / 200;                // 8000 (exact)
        const int4* d4 = (const int4*)(dst + sb * SLICE);
        const int4* s4 = (const int4*)(src + sb * SLICE);
        const int nvec = SLICE / 4;               // 2000
        for (int v = threadIdx.x; v < nvec; v += 256) {
            int4 dd = d4[v];
            int4 ss = s4[v];
            if (dd.x >= lo && dd.x < hi) e_src[atomicAdd(&cursor[dd.x], 1)] = ss.x;
            if (dd.y >= lo && dd.y < hi) e_src[atomicAdd(&cursor[dd.y], 1)] = ss.y;
            if (dd.z >= lo && dd.z < hi) e_src[atomicAdd(&cursor[dd.z], 1)] = ss.z;
            if (dd.w >= lo && dd.w < hi) e_src[atomicAdd(&cursor[dd.w], 1)] = ss.w;
        }
    } else {
        // ---- GEMM role ----
        const int bx = (g >> 1) * 8 + (blockIdx.x & 7);   // 0..1599
        if (bx * 64 < N)
            gemm_body<9, 128, 128, false, false, float>(bx, A, Wt, C, elh, er, nullptr, N);
    }
}

// ---------------------------------------------------------------- layer-1 gather (fused edge weights, fp16 el table)
// 4-wide flat loop: proven optimum (R3 pipeline, R4 8-wide, R8 alpha-precompute,
// R10 nt-loads all regressed).  Fetch-bound at ~3 TB/s (R8 decisive: VALU 76->41%
// with zero duration change).
__global__ __launch_bounds__(256) void gat_gather1(
    const __half* __restrict__ feat, const __half* __restrict__ elh,
    const float* __restrict__ er,
    const int* __restrict__ row_ptr, const int* __restrict__ e_src,
    const float* __restrict__ bias, __half* __restrict__ out) {
    const int t = threadIdx.x;
    const int lane = t & 63;
    const int n = blockIdx.x * 4 + (t >> 6);
    const int h = lane >> 4;
    const int start = row_ptr[n], end = row_ptr[n + 1];
    const char* fb = (const char*)feat;
    const uint32_t flo = (uint32_t)lane * 4u;
    const float ern = er[n * 4 + h];
    float ax = 0.f, ay = 0.f, s = 0.f;
    int i = start;
    for (; i + 4 <= end; i += 4) {
        int sv0 = e_src[i + 0], sv1 = e_src[i + 1], sv2 = e_src[i + 2], sv3 = e_src[i + 3];
        float e0 = __half2float(elh[sv0 * 4 + h]) + ern;
        float e1 = __half2float(elh[sv1 * 4 + h]) + ern;
        float e2 = __half2float(elh[sv2 * 4 + h]) + ern;
        float e3 = __half2float(elh[sv3 * 4 + h]) + ern;
        float w0 = __expf(fmaxf(e0, 0.2f * e0));
        float w1 = __expf(fmaxf(e1, 0.2f * e1));
        float w2 = __expf(fmaxf(e2, 0.2f * e2));
        float w3 = __expf(fmaxf(e3, 0.2f * e3));
        __half2 f0 = *(const __half2*)(fb + (uint32_t)sv0 * 256u + flo);
        __half2 f1 = *(const __half2*)(fb + (uint32_t)sv1 * 256u + flo);
        __half2 f2v = *(const __half2*)(fb + (uint32_t)sv2 * 256u + flo);
        __half2 f3 = *(const __half2*)(fb + (uint32_t)sv3 * 256u + flo);
        float2 g0 = __half22float2(f0), g1 = __half22float2(f1);
        float2 g2 = __half22float2(f2v), g3 = __half22float2(f3);
        s += (w0 + w1) + (w2 + w3);
        ax += w0 * g0.x + w1 * g1.x + w2 * g2.x + w3 * g3.x;
        ay += w0 * g0.y + w1 * g1.y + w2 * g2.y + w3 * g3.y;
    }
    for (; i < end; ++i) {
        int sv = e_src[i];
        float e = __half2float(elh[sv * 4 + h]) + ern;
        float ww = __expf(fmaxf(e, 0.2f * e));
        float2 g = __half22float2(*(const __half2*)(fb + (uint32_t)sv * 256u + flo));
        s += ww;
        ax += ww * g.x;
        ay += ww * g.y;
    }
    float inv = 1.f / fmaxf(s, 1e-9f);
    float ox = ax * inv + bias[lane * 2 + 0];
    float oy = ay * inv + bias[lane * 2 + 1];
    ox = (ox > 0.f) ? ox : (__expf(ox) - 1.f);
    oy = (oy > 0.f) ? oy : (__expf(oy) - 1.f);
    ((__half2*)out)[(size_t)n * 64 + lane] = __floats2half2_rn(ox, oy);
}

// ---------------------------------------------------------------- layer-2 gather (el embedded in feat pad slots)
// R2-measured optimum (101 µs): el2 rides the feature row's cache lines (pad slot
// h*48+47), extracted with one shfl per edge from lane g11's f[3].  Failed-variant
// ledger: R1 lane-restructure (120), R3 pipeline (105.8), R4 8-wide (102.8),
// R6 elh2 table (110.6, +30MB FETCH), R8 alpha-precompute (VALU 41%, dur flat ->
// FETCH-BOUND; 278MB = 8 XCD x ~35MB feat2 L2 duplication, structural for random
// graphs), R10 nt-loads (564 total).
__global__ __launch_bounds__(256) void gat_gather2(
    const __half* __restrict__ feat, const float* __restrict__ er,
    const int* __restrict__ row_ptr, const int* __restrict__ e_src,
    const float* __restrict__ bias, float* __restrict__ out) {
    const int t = threadIdx.x;
    const int lane = t & 63;
    const int n = blockIdx.x * 4 + (t >> 6);
    if (lane < 48) {
        const int h = lane / 12;
        const int q = lane - h * 12;
        const int g11 = h * 12 + 11;         // lane holding el_h in f[3]
        const int start = row_ptr[n], end = row_ptr[n + 1];
        const char* fb = (const char*)feat;
        const uint32_t flo = (uint32_t)lane * 8u;
        const float ern = er[n * 4 + h];
        float a0 = 0.f, a1 = 0.f, a2 = 0.f, a3 = 0.f, s = 0.f;
        int i = start;
        for (; i + 4 <= end; i += 4) {
            int sv0 = e_src[i + 0], sv1 = e_src[i + 1], sv2 = e_src[i + 2], sv3 = e_src[i + 3];
            half4_t f0 = *(const half4_t*)(fb + (uint32_t)sv0 * 384u + flo);
            half4_t f1 = *(const half4_t*)(fb + (uint32_t)sv1 * 384u + flo);
            half4_t f2 = *(const half4_t*)(fb + (uint32_t)sv2 * 384u + flo);
            half4_t f3 = *(const half4_t*)(fb + (uint32_t)sv3 * 384u + flo);
            float e0 = __shfl((float)f0[3], g11, 64) + ern;
            float e1 = __shfl((float)f1[3], g11, 64) + ern;
            float e2 = __shfl((float)f2[3], g11, 64) + ern;
            float e3 = __shfl((float)f3[3], g11, 64) + ern;
            float w0 = __expf(fmaxf(e0, 0.2f * e0));
            float w1 = __expf(fmaxf(e1, 0.2f * e1));
            float w2 = __expf(fmaxf(e2, 0.2f * e2));
            float w3 = __expf(fmaxf(e3, 0.2f * e3));
            s += (w0 + w1) + (w2 + w3);
            a0 += w0 * (float)f0[0] + w1 * (float)f1[0] + w2 * (float)f2[0] + w3 * (float)f3[0];
            a1 += w0 * (float)f0[1] + w1 * (float)f1[1] + w2 * (float)f2[1] + w3 * (float)f3[1];
            a2 += w0 * (float)f0[2] + w1 * (float)f1[2] + w2 * (float)f2[2] + w3 * (float)f3[2];
            a3 += w0 * (float)f0[3] + w1 * (float)f1[3] + w2 * (float)f2[3] + w3 * (float)f3[3];
        }
        for (; i < end; ++i) {
            int sv = e_src[i];
            half4_t f0 = *(const half4_t*)(fb + (uint32_t)sv * 384u + flo);
            float e = __shfl((float)f0[3], g11, 64) + ern;
            float ww = __expf(fmaxf(e, 0.2f * e));
            s += ww;
            a0 += ww * (float)f0[0];
            a1 += ww * (float)f0[1];
            a2 += ww * (float)f0[2];
            a3 += ww * (float)f0[3];
        }
        if (q == 11) a3 = 0.f;               // pad col (holds el) — mask from accumulator
        float inv = 1.f / fmaxf(s, 1e-9f);
        const int d0 = q * 4;
        float b0 = bias[h * 47 + d0 + 0];
        float b1 = bias[h * 47 + d0 + 1];
        float b2 = bias[h * 47 + d0 + 2];
        float b3 = (d0 + 3 < 47) ? bias[h * 47 + d0 + 3] : 0.f;
        float r0 = a0 * inv + b0;
        float r1 = a1 * inv + b1;
        float r2 = a2 * inv + b2;
        float r3 = a3 * inv + b3;
        float t0 = r0 + __shfl(r0, lane + 12, 64) + __shfl(r0, lane + 24, 64) + __shfl(r0, lane + 36, 64);
        float t1 = r1 + __shfl(r1, lane + 12, 64) + __shfl(r1, lane + 24, 64) + __shfl(r1, lane + 36, 64);
        float t2 = r2 + __shfl(r2, lane + 12, 64) + __shfl(r2, lane + 24, 64) + __shfl(r2, lane + 36, 64);
        float t3 = r3 + __shfl(r3, lane + 12, 64) + __shfl(r3, lane + 24, 64) + __shfl(r3, lane + 36, 64);
        if (h == 0) {
            size_t base = (size_t)n * 47 + d0;
            out[base + 0] = 0.25f * t0;
            out[base + 1] = 0.25f * t1;
            out[base + 2] = 0.25f * t2;
            if (d0 + 3 < 47) out[base + 3] = 0.25f * t3;
        }
    }
}

// ---------------------------------------------------------------- launcher
extern "C" void kernel_launch(void* const* d_in, const int* in_sizes, int n_in,
                              void* d_out, int out_size, void* d_ws, size_t ws_size,
                              hipStream_t stream) {
    const int N = N_NODES, E = N_EDGES;
    const float* x    = (const float*)d_in[0];
    const int*   src  = (const int*)d_in[1];
    const int*   dst  = (const int*)d_in[2];
    const int*   inv  = (const int*)d_in[3];
    const float* W1   = (const float*)d_in[4];
    const float* al1  = (const float*)d_in[5];
    const float* ar1  = (const float*)d_in[6];
    const float* b1   = (const float*)d_in[7];
    const float* W2   = (const float*)d_in[8];
    const float* al2  = (const float*)d_in[9];
    const float* ar2  = (const float*)d_in[10];
    const float* b2   = (const float*)d_in[11];
    float* out = (float*)d_out;

    char* p = (char*)d_ws;
    auto carve = [&](size_t bytes) {
        char* q = p;
        p += (bytes + 255) & ~size_t(255);
        return q;
    };
    __half* feat1   = (__half*)carve((size_t)N * 128 * 2);
    __half* feat2   = (__half*)carve((size_t)N * 192 * 2);  // padded h*48+d; pad slot h*48+47 = el2(h) fp16
    __half* hbuf    = (__half*)carve((size_t)N * 128 * 2);
    __half* Wt1     = (__half*)carve(144 * 128 * 2);
    __half* Wt2     = (__half*)carve(208 * 128 * 2);
    __half* elh1    = (__half*)carve((size_t)N * 4 * 2);
    float*  er      = (float*)carve((size_t)N * 4 * 4);
    int*    deg     = (int*)carve((size_t)N * 4);
    int*    row_ptr = (int*)carve((size_t)(N + 1) * 4);
    int*    cursor  = (int*)carve((size_t)N * 4);
    int*    bsum    = (int*)carve(512 * 4);
    int*    e_src   = (int*)carve((size_t)E * 4);

    const int nb = (N + 255) / 256;  // 391

    // ---- CSR build + weight prep (fused count_deg + prep_w) ----
    hipMemsetAsync(deg, 0, (size_t)N * 4, stream);
    csr_prep<<<6250 + 352, 256, 0, stream>>>(dst, deg, E, W1, W2, al1, ar1, al2, ar2, Wt1, Wt2);
    block_sums<<<nb, 256, 0, stream>>>(deg, bsum, N);
    scan_bsum<<<1, 512, 0, stream>>>(bsum, nb);
    scan_final<<<nb, 256, 0, stream>>>(deg, bsum, row_ptr, cursor, N);

    // ---- fused scatter + layer-1 GEMM (independent work, co-resident) ----
    scatter_gemm1<<<3200, 256, 0, stream>>>(src, dst, cursor, e_src, E,
                                            x, Wt1, feat1, elh1, er, N);

    // ---- layer 1 aggregate ----
    gat_gather1<<<(N + 3) / 4, 256, 0, stream>>>(feat1, elh1, er, row_ptr, e_src, b1, hbuf);

    // ---- layer 2 (rows gathered through inverse_idx; el2 embedded in feat2 pad) ----
    gemm_mfma<13, 188, 192, true, true, __half><<<(N + 63) / 64, 256, 0, stream>>>(
        hbuf, Wt2, feat2, nullptr, er, inv, N);
    gat_gather2<<<(N + 3) / 4, 256, 0, stream>>>(feat2, er, row_ptr, e_src, b2, out);
}